// Round 7
// baseline (3122.218 us; speedup 1.0000x reference)
//
#include <hip/hip_runtime.h>
#include <hip/hip_bf16.h>
#include <stddef.h>

// Problem constants (match reference setup_inputs)
#define N_NODES 100000
#define N_EDGES 20000
#define NNZ     1600000
#define DIM     128

// Coarse-bucket config
#define NBLK    512                 // bucket-build blocks (full occupancy)
#define CHUNK   (NNZ / NBLK)        // 3125 exactly
#define NBUCK_E 313                 // ceil(20000/64): bucket = e >> 6
#define NBUCK_N 782                 // ceil(100000/128): bucket = n >> 7
#define ACC_STR 132                 // f32 accumulator row stride (+4 pad: bank spread)

typedef short          bf16x8 __attribute__((ext_vector_type(8)));
typedef unsigned short u16x8  __attribute__((ext_vector_type(8)));
typedef float          f32x4  __attribute__((ext_vector_type(4)));
typedef float          f32x8  __attribute__((ext_vector_type(8)));

__device__ __forceinline__ unsigned short f2bf(float f) {
  union { float f; unsigned u; } c; c.f = f;
  unsigned r = c.u + 0x7FFFu + ((c.u >> 16) & 1u);   // round-to-nearest-even
  return (unsigned short)(r >> 16);
}

__device__ __forceinline__ f32x8 bf2f8(u16x8 v) {
  f32x8 r;
  #pragma unroll
  for (int i = 0; i < 8; ++i) {
    union { unsigned u; float f; } c; c.u = ((unsigned)v[i]) << 16;
    r[i] = c.f;
  }
  return r;
}

// ---------------- W fp32 -> bf16 ----------------
__global__ void convw_kernel(const float* __restrict__ W, unsigned short* __restrict__ Wb) {
  int i = blockIdx.x * 256 + threadIdx.x;
  if (i < DIM * DIM) Wb[i] = f2bf(W[i]);
}

// ---------------- GEMM: hb = bf16(x @ W^T + b) ----------------
__global__ __launch_bounds__(256) void gemm_kernel(
    const float* __restrict__ x, const unsigned short* __restrict__ Wb,
    const float* __restrict__ bias, unsigned short* __restrict__ hb) {
  const int wid = threadIdx.x >> 6;
  const int l   = threadIdx.x & 63;
  const int n0  = (blockIdx.x * 4 + wid) * 16;
  if (n0 >= N_NODES) return;
  const int r  = l & 15;   // A-row within tile / B-fragment row
  const int kg = l >> 4;   // k-group (8 consecutive k per group)

  bf16x8 a[4];
  {
    const float* xr = x + (size_t)(n0 + r) * DIM + kg * 8;
    #pragma unroll
    for (int kc = 0; kc < 4; ++kc) {
      const float4* p = reinterpret_cast<const float4*>(xr + kc * 32);
      float4 f0 = p[0], f1 = p[1];
      bf16x8 av;
      av[0]=(short)f2bf(f0.x); av[1]=(short)f2bf(f0.y); av[2]=(short)f2bf(f0.z); av[3]=(short)f2bf(f0.w);
      av[4]=(short)f2bf(f1.x); av[5]=(short)f2bf(f1.y); av[6]=(short)f2bf(f1.z); av[7]=(short)f2bf(f1.w);
      a[kc] = av;
    }
  }

  f32x4 acc[8];
  #pragma unroll
  for (int ot = 0; ot < 8; ++ot) acc[ot] = (f32x4){0.f, 0.f, 0.f, 0.f};

  #pragma unroll
  for (int ot = 0; ot < 8; ++ot) {
    // permuted: o-tile ot, fragment row r <- W row (r*8 + ot)
    const unsigned short* wr = Wb + (size_t)(r * 8 + ot) * DIM + kg * 8;
    #pragma unroll
    for (int kc = 0; kc < 4; ++kc) {
      bf16x8 bfrag = *reinterpret_cast<const bf16x8*>(wr + kc * 32);
      acc[ot] = __builtin_amdgcn_mfma_f32_16x16x32_bf16(a[kc], bfrag, acc[ot], 0, 0, 0);
    }
  }

  float bv[8];
  {
    const float4* bp = reinterpret_cast<const float4*>(bias + r * 8);
    float4 b0 = bp[0], b1 = bp[1];
    bv[0]=b0.x; bv[1]=b0.y; bv[2]=b0.z; bv[3]=b0.w;
    bv[4]=b1.x; bv[5]=b1.y; bv[6]=b1.z; bv[7]=b1.w;
  }

  // C/D: col(fragrow)=lane&15, row=(lane>>4)*4+reg [m89]; col r of tile ot = channel r*8+ot
  #pragma unroll
  for (int j = 0; j < 4; ++j) {
    const int row = kg * 4 + j;
    u16x8 hv;
    #pragma unroll
    for (int ot = 0; ot < 8; ++ot) hv[ot] = f2bf(acc[ot][j] + bv[ot]);
    *reinterpret_cast<u16x8*>(&hb[(size_t)(n0 + row) * DIM + r * 8]) = hv;
  }
}

// ---------------- bucket histograms (both sides, one pass, LDS bins) ----------------
// bh layout is bucket-major: bh[bucket * NBLK + blk]
__global__ __launch_bounds__(256) void bhist2_kernel(
    const int* __restrict__ ni, const int* __restrict__ ei,
    int* __restrict__ bhE, int* __restrict__ bhN) {
  __shared__ int he[NBUCK_E];
  __shared__ int hn[NBUCK_N];
  for (int k = threadIdx.x; k < NBUCK_E; k += 256) he[k] = 0;
  for (int k = threadIdx.x; k < NBUCK_N; k += 256) hn[k] = 0;
  __syncthreads();
  const int base = blockIdx.x * CHUNK;
  for (int i = base + threadIdx.x; i < base + CHUNK; i += 256) {
    atomicAdd(&he[ei[i] >> 6], 1);
    atomicAdd(&hn[ni[i] >> 7], 1);
  }
  __syncthreads();
  for (int k = threadIdx.x; k < NBUCK_E; k += 256) bhE[(size_t)k * NBLK + blockIdx.x] = he[k];
  for (int k = threadIdx.x; k < NBUCK_N; k += 256) bhN[(size_t)k * NBLK + blockIdx.x] = hn[k];
}

// ---------------- hierarchical exclusive scan ----------------
__global__ void scan_block_kernel(const int* __restrict__ in, int* __restrict__ out,
                                  int* __restrict__ bsums, int n) {
  __shared__ int lds[1024];
  const int tx = threadIdx.x;
  const int i  = blockIdx.x * blockDim.x + tx;
  int v = (i < n) ? in[i] : 0;
  int x = v;
  lds[tx] = x;
  __syncthreads();
  for (int off = 1; off < (int)blockDim.x; off <<= 1) {
    int t = (tx >= off) ? lds[tx - off] : 0;
    __syncthreads();
    x += t;
    lds[tx] = x;
    __syncthreads();
  }
  if (i < n) out[i] = x - v;                 // exclusive
  if (bsums && tx == (int)blockDim.x - 1) bsums[blockIdx.x] = x;  // total
}

__global__ void scan_add_kernel(int* __restrict__ out, const int* __restrict__ bsums, int n) {
  int i = blockIdx.x * blockDim.x + threadIdx.x;
  if (i < n) out[i] += bsums[blockIdx.x];
}

// ---------------- bucket scatter (both sides): fold-init LDS cursors, packed u32 ----------------
// pack = (n << 15) | e   (n < 2^17, e < 2^15)
__global__ __launch_bounds__(256) void bscatter2_kernel(
    const int* __restrict__ ni, const int* __restrict__ ei,
    const int* __restrict__ scE, const int* __restrict__ scN,
    unsigned* __restrict__ packedE, unsigned* __restrict__ packedN) {
  __shared__ int ce[NBUCK_E];
  __shared__ int cn[NBUCK_N];
  for (int k = threadIdx.x; k < NBUCK_E; k += 256) ce[k] = scE[(size_t)k * NBLK + blockIdx.x];
  for (int k = threadIdx.x; k < NBUCK_N; k += 256) cn[k] = scN[(size_t)k * NBLK + blockIdx.x];
  __syncthreads();
  const int base = blockIdx.x * CHUNK;
  for (int i = base + threadIdx.x; i < base + CHUNK; i += 256) {
    int n = ni[i], e = ei[i];
    unsigned p = ((unsigned)n << 15) | (unsigned)e;
    packedE[atomicAdd(&ce[e >> 6], 1)] = p;
    packedN[atomicAdd(&cn[n >> 7], 1)] = p;
  }
}

// ---------------- hop 1: per e-bucket LDS f32 accumulate -> m01b ----------------
// 512 threads = 32 groups x 16 lanes; group streams elements (stride 32, 4-deep).
__global__ __launch_bounds__(512) void hop1_kernel(
    const unsigned short* __restrict__ hb, const int* __restrict__ scE,
    const unsigned* __restrict__ packedE, unsigned short* __restrict__ m01b) {
  __shared__ float acc[64 * ACC_STR];   // 33.8 KB
  const int b = blockIdx.x;
  for (int k = threadIdx.x; k < 64 * ACC_STR; k += 512) acc[k] = 0.f;
  const int start = scE[(size_t)b * NBLK];
  const int end   = (b + 1 < NBUCK_E) ? scE[(size_t)(b + 1) * NBLK] : NNZ;
  __syncthreads();
  const int g = threadIdx.x >> 4;   // 0..31
  const int l = threadIdx.x & 15;

  int j = start + g;
  for (; j + 96 < end; j += 128) {
    unsigned p0 = packedE[j];
    unsigned p1 = packedE[j + 32];
    unsigned p2 = packedE[j + 64];
    unsigned p3 = packedE[j + 96];
    u16x8 v0 = *reinterpret_cast<const u16x8*>(&hb[(size_t)(p0 >> 15) * DIM + l * 8]);
    u16x8 v1 = *reinterpret_cast<const u16x8*>(&hb[(size_t)(p1 >> 15) * DIM + l * 8]);
    u16x8 v2 = *reinterpret_cast<const u16x8*>(&hb[(size_t)(p2 >> 15) * DIM + l * 8]);
    u16x8 v3 = *reinterpret_cast<const u16x8*>(&hb[(size_t)(p3 >> 15) * DIM + l * 8]);
    f32x8 f0 = bf2f8(v0), f1 = bf2f8(v1), f2 = bf2f8(v2), f3 = bf2f8(v3);
    float* a0 = &acc[(p0 & 63u) * ACC_STR + l * 8];
    float* a1 = &acc[(p1 & 63u) * ACC_STR + l * 8];
    float* a2 = &acc[(p2 & 63u) * ACC_STR + l * 8];
    float* a3 = &acc[(p3 & 63u) * ACC_STR + l * 8];
    #pragma unroll
    for (int m = 0; m < 8; ++m) atomicAdd(&a0[m], f0[m]);
    #pragma unroll
    for (int m = 0; m < 8; ++m) atomicAdd(&a1[m], f1[m]);
    #pragma unroll
    for (int m = 0; m < 8; ++m) atomicAdd(&a2[m], f2[m]);
    #pragma unroll
    for (int m = 0; m < 8; ++m) atomicAdd(&a3[m], f3[m]);
  }
  for (; j < end; j += 32) {
    unsigned p = packedE[j];
    u16x8 v = *reinterpret_cast<const u16x8*>(&hb[(size_t)(p >> 15) * DIM + l * 8]);
    f32x8 f = bf2f8(v);
    float* a = &acc[(p & 63u) * ACC_STR + l * 8];
    #pragma unroll
    for (int m = 0; m < 8; ++m) atomicAdd(&a[m], f[m]);
  }
  __syncthreads();

  // writeout: 64 edges x 16 segs of 8 dims
  for (int k = threadIdx.x; k < 64 * 16; k += 512) {
    const int eloc = k >> 4, seg = k & 15;
    const int eg = b * 64 + eloc;
    if (eg < N_EDGES) {
      const float* a = &acc[eloc * ACC_STR + seg * 8];
      u16x8 o;
      #pragma unroll
      for (int m = 0; m < 8; ++m) o[m] = f2bf(a[m]);
      *reinterpret_cast<u16x8*>(&m01b[(size_t)eg * DIM + seg * 8]) = o;
    }
  }
}

// ---------------- hop 2: per n-bucket LDS f32 accumulate + deg + residual -> out ----------------
__global__ __launch_bounds__(512) void hop2_kernel(
    const unsigned short* __restrict__ hb, const int* __restrict__ scN,
    const unsigned* __restrict__ packedN, const unsigned short* __restrict__ m01b,
    float* __restrict__ out) {
  __shared__ float acc[128 * ACC_STR];   // 67.6 KB
  __shared__ int   degL[128];
  const int b = blockIdx.x;
  for (int k = threadIdx.x; k < 128 * ACC_STR; k += 512) acc[k] = 0.f;
  for (int k = threadIdx.x; k < 128; k += 512) degL[k] = 0;
  const int start = scN[(size_t)b * NBLK];
  const int end   = (b + 1 < NBUCK_N) ? scN[(size_t)(b + 1) * NBLK] : NNZ;
  __syncthreads();
  const int g = threadIdx.x >> 4;   // 0..31
  const int l = threadIdx.x & 15;

  int j = start + g;
  for (; j + 96 < end; j += 128) {
    unsigned p0 = packedN[j];
    unsigned p1 = packedN[j + 32];
    unsigned p2 = packedN[j + 64];
    unsigned p3 = packedN[j + 96];
    u16x8 v0 = *reinterpret_cast<const u16x8*>(&m01b[(size_t)(p0 & 0x7FFFu) * DIM + l * 8]);
    u16x8 v1 = *reinterpret_cast<const u16x8*>(&m01b[(size_t)(p1 & 0x7FFFu) * DIM + l * 8]);
    u16x8 v2 = *reinterpret_cast<const u16x8*>(&m01b[(size_t)(p2 & 0x7FFFu) * DIM + l * 8]);
    u16x8 v3 = *reinterpret_cast<const u16x8*>(&m01b[(size_t)(p3 & 0x7FFFu) * DIM + l * 8]);
    f32x8 f0 = bf2f8(v0), f1 = bf2f8(v1), f2 = bf2f8(v2), f3 = bf2f8(v3);
    float* a0 = &acc[((p0 >> 15) & 127u) * ACC_STR + l * 8];
    float* a1 = &acc[((p1 >> 15) & 127u) * ACC_STR + l * 8];
    float* a2 = &acc[((p2 >> 15) & 127u) * ACC_STR + l * 8];
    float* a3 = &acc[((p3 >> 15) & 127u) * ACC_STR + l * 8];
    if (l == 0) {
      atomicAdd(&degL[(p0 >> 15) & 127u], 1);
      atomicAdd(&degL[(p1 >> 15) & 127u], 1);
      atomicAdd(&degL[(p2 >> 15) & 127u], 1);
      atomicAdd(&degL[(p3 >> 15) & 127u], 1);
    }
    #pragma unroll
    for (int m = 0; m < 8; ++m) atomicAdd(&a0[m], f0[m]);
    #pragma unroll
    for (int m = 0; m < 8; ++m) atomicAdd(&a1[m], f1[m]);
    #pragma unroll
    for (int m = 0; m < 8; ++m) atomicAdd(&a2[m], f2[m]);
    #pragma unroll
    for (int m = 0; m < 8; ++m) atomicAdd(&a3[m], f3[m]);
  }
  for (; j < end; j += 32) {
    unsigned p = packedN[j];
    u16x8 v = *reinterpret_cast<const u16x8*>(&m01b[(size_t)(p & 0x7FFFu) * DIM + l * 8]);
    f32x8 f = bf2f8(v);
    float* a = &acc[((p >> 15) & 127u) * ACC_STR + l * 8];
    if (l == 0) atomicAdd(&degL[(p >> 15) & 127u], 1);
    #pragma unroll
    for (int m = 0; m < 8; ++m) atomicAdd(&a[m], f[m]);
  }
  __syncthreads();

  // writeout: 128 nodes x 16 segs; out = h + acc/deg
  for (int k = threadIdx.x; k < 128 * 16; k += 512) {
    const int nloc = k >> 4, seg = k & 15;
    const int ng = b * 128 + nloc;
    if (ng < N_NODES) {
      const int cnt = degL[nloc];
      const float inv = 1.0f / (float)(cnt > 0 ? cnt : 1);
      f32x8 hv = bf2f8(*reinterpret_cast<const u16x8*>(&hb[(size_t)ng * DIM + seg * 8]));
      const float* a = &acc[nloc * ACC_STR + seg * 8];
      float* op = &out[(size_t)ng * DIM + seg * 8];
      f32x4 o0 = (f32x4){hv[0] + a[0] * inv, hv[1] + a[1] * inv,
                         hv[2] + a[2] * inv, hv[3] + a[3] * inv};
      f32x4 o1 = (f32x4){hv[4] + a[4] * inv, hv[5] + a[5] * inv,
                         hv[6] + a[6] * inv, hv[7] + a[7] * inv};
      *reinterpret_cast<f32x4*>(op)     = o0;
      *reinterpret_cast<f32x4*>(op + 4) = o1;
    }
  }
}

extern "C" void kernel_launch(void* const* d_in, const int* in_sizes, int n_in,
                              void* d_out, int out_size, void* d_ws, size_t ws_size,
                              hipStream_t stream) {
  const float* x    = (const float*)d_in[0];
  const float* W    = (const float*)d_in[1];
  const float* bias = (const float*)d_in[2];
  const int*   ni   = (const int*)d_in[3];
  const int*   ei   = (const int*)d_in[4];
  float* out = (float*)d_out;

  // ---- workspace carve ----
  char* ws = (char*)d_ws;
  size_t o = 0;
  auto carve = [&](size_t bytes) -> char* {
    char* p = ws + o;
    o = (o + bytes + 255) & ~(size_t)255;
    return p;
  };
  unsigned short* hb      = (unsigned short*)carve((size_t)N_NODES * DIM * 2);   // 25.6 MB
  unsigned short* m01b    = (unsigned short*)carve((size_t)N_EDGES * DIM * 2);   // 5.12 MB
  unsigned short* Wb      = (unsigned short*)carve((size_t)DIM * DIM * 2);       // 32 KB
  int*            bhE     = (int*)           carve((size_t)NBUCK_E * NBLK * 4);  // 641 KB
  int*            bhN     = (int*)           carve((size_t)NBUCK_N * NBLK * 4);  // 1.6 MB
  unsigned*       packedE = (unsigned*)      carve((size_t)NNZ * 4);             // 6.4 MB
  unsigned*       packedN = (unsigned*)      carve((size_t)NNZ * 4);             // 6.4 MB
  int*            bsE     = (int*)           carve(1024 * 4);
  int*            bsN     = (int*)           carve(1024 * 4);
  (void)ws_size; (void)in_sizes; (void)n_in; (void)out_size;

  // ---- W -> bf16, GEMM ----
  convw_kernel<<<(DIM * DIM + 255) / 256, 256, 0, stream>>>(W, Wb);
  gemm_kernel<<<(N_NODES / 16 + 3) / 4, 256, 0, stream>>>(x, Wb, bias, hb);

  // ---- bucket histograms (both sides) ----
  bhist2_kernel<<<NBLK, 256, 0, stream>>>(ni, ei, bhE, bhN);

  // ---- exclusive scans over (bucket, block), bucket-major: absolute offsets ----
  {
    const int nE = NBUCK_E * NBLK;   // 160256 = 313 * 512
    scan_block_kernel<<<NBUCK_E, 512, 0, stream>>>(bhE, bhE, bsE, nE);
    scan_block_kernel<<<1, 512, 0, stream>>>(bsE, bsE, nullptr, NBUCK_E);
    scan_add_kernel<<<NBUCK_E, 512, 0, stream>>>(bhE, bsE, nE);

    const int nN = NBUCK_N * NBLK;   // 400384 = 782 * 512
    scan_block_kernel<<<NBUCK_N, 512, 0, stream>>>(bhN, bhN, bsN, nN);
    scan_block_kernel<<<1, 1024, 0, stream>>>(bsN, bsN, nullptr, NBUCK_N);
    scan_add_kernel<<<NBUCK_N, 512, 0, stream>>>(bhN, bsN, nN);
  }

  // ---- bucket scatter (packed u32, both sides) ----
  bscatter2_kernel<<<NBLK, 256, 0, stream>>>(ni, ei, bhE, bhN, packedE, packedN);

  // ---- hops: LDS f32 bucket accumulation ----
  hop1_kernel<<<NBUCK_E, 512, 0, stream>>>(hb, bhE, packedE, m01b);
  hop2_kernel<<<NBUCK_N, 512, 0, stream>>>(hb, bhN, packedN, m01b, out);
}

// Round 8
// 297.536 us; speedup vs baseline: 10.4936x; 10.4936x over previous
//
#include <hip/hip_runtime.h>
#include <hip/hip_bf16.h>
#include <stddef.h>

// Problem constants (match reference setup_inputs)
#define N_NODES 100000
#define N_EDGES 20000
#define NNZ     1600000
#define DIM     128

// Edge LDS-histogram config
#define EH_BLOCKS  64
#define EH_CHUNK   (NNZ / EH_BLOCKS)   // 25000 exactly

// p1 fused-kernel role layout: [ehist 64][gemm 391][nhist 1563]
#define GEMM_B0   64
#define GEMM_NB   391                   // ceil(100000 / 256) rows per block
#define NHIST_B0  (GEMM_B0 + GEMM_NB)   // 455
#define NHIST_NB  1563                  // 1563*1024 >= NNZ
#define P1_NB     (NHIST_B0 + NHIST_NB) // 2018

typedef short          bf16x8 __attribute__((ext_vector_type(8)));
typedef unsigned short u16x8  __attribute__((ext_vector_type(8)));
typedef float          f32x4  __attribute__((ext_vector_type(4)));
typedef float          f32x8  __attribute__((ext_vector_type(8)));

__device__ __forceinline__ unsigned short f2bf(float f) {
  union { float f; unsigned u; } c; c.f = f;
  unsigned r = c.u + 0x7FFFu + ((c.u >> 16) & 1u);   // round-to-nearest-even
  return (unsigned short)(r >> 16);
}

__device__ __forceinline__ f32x8 bf2f8(u16x8 v) {
  f32x8 r;
  #pragma unroll
  for (int i = 0; i < 8; ++i) {
    union { unsigned u; float f; } c; c.u = ((unsigned)v[i]) << 16;
    r[i] = c.f;
  }
  return r;
}

// ---------------- W fp32 -> bf16 ----------------
__global__ void convw_kernel(const float* __restrict__ W, unsigned short* __restrict__ Wb) {
  int i = blockIdx.x * 256 + threadIdx.x;
  if (i < DIM * DIM) Wb[i] = f2bf(W[i]);
}

// ---------------- p1: fused [ehist | gemm | nhist] ----------------
// ehist: per-chunk LDS edge histogram; stores within-(edge,chunk) rank locE and
//        per-(edge,chunk) counts bhE (bucket-major).
// gemm:  hb = bf16(x @ W^T + b), 1024 thr = 16 waves, wave = 16 rows x 128 cols.
// nhist: node degree histogram via global atomic-returns -> rank_n.
__global__ __launch_bounds__(1024, 8) void p1_kernel(
    const float* __restrict__ x, const unsigned short* __restrict__ Wb,
    const float* __restrict__ bias, unsigned short* __restrict__ hb,
    const int* __restrict__ ni, const int* __restrict__ ei,
    int* __restrict__ bhE, unsigned short* __restrict__ locE,
    int* __restrict__ deg_n, unsigned short* __restrict__ rank_n) {
  __shared__ int hist[N_EDGES];   // 80 KB (ehist role only; 2 blocks/CU)
  const int bid = blockIdx.x;

  if (bid < GEMM_B0) {
    // ---- ehist role ----
    for (int k = threadIdx.x; k < N_EDGES; k += 1024) hist[k] = 0;
    __syncthreads();
    const int base = bid * EH_CHUNK;
    for (int i = base + threadIdx.x; i < base + EH_CHUNK; i += 1024) {
      int e = ei[i];
      locE[i] = (unsigned short)atomicAdd(&hist[e], 1);
    }
    __syncthreads();
    for (int k = threadIdx.x; k < N_EDGES; k += 1024)
      bhE[(size_t)k * EH_BLOCKS + bid] = hist[k];
  } else if (bid < NHIST_B0) {
    // ---- gemm role ----
    const int wid = threadIdx.x >> 6;            // 0..15
    const int l   = threadIdx.x & 63;
    const int n0  = ((bid - GEMM_B0) * 16 + wid) * 16;
    if (n0 >= N_NODES) return;
    const int r  = l & 15;   // A-row within tile / B-fragment row
    const int kg = l >> 4;   // k-group (8 consecutive k per group)

    bf16x8 a[4];
    {
      const float* xr = x + (size_t)(n0 + r) * DIM + kg * 8;
      #pragma unroll
      for (int kc = 0; kc < 4; ++kc) {
        const float4* p = reinterpret_cast<const float4*>(xr + kc * 32);
        float4 f0 = p[0], f1 = p[1];
        bf16x8 av;
        av[0]=(short)f2bf(f0.x); av[1]=(short)f2bf(f0.y); av[2]=(short)f2bf(f0.z); av[3]=(short)f2bf(f0.w);
        av[4]=(short)f2bf(f1.x); av[5]=(short)f2bf(f1.y); av[6]=(short)f2bf(f1.z); av[7]=(short)f2bf(f1.w);
        a[kc] = av;
      }
    }

    f32x4 acc[8];
    #pragma unroll
    for (int ot = 0; ot < 8; ++ot) acc[ot] = (f32x4){0.f, 0.f, 0.f, 0.f};

    #pragma unroll
    for (int ot = 0; ot < 8; ++ot) {
      // permuted: o-tile ot, fragment row r <- W row (r*8 + ot)
      const unsigned short* wr = Wb + (size_t)(r * 8 + ot) * DIM + kg * 8;
      #pragma unroll
      for (int kc = 0; kc < 4; ++kc) {
        bf16x8 bfrag = *reinterpret_cast<const bf16x8*>(wr + kc * 32);
        acc[ot] = __builtin_amdgcn_mfma_f32_16x16x32_bf16(a[kc], bfrag, acc[ot], 0, 0, 0);
      }
    }

    // bias for this lane's 8 consecutive channels (loaded after MFMA: reg pressure)
    float bv[8];
    {
      const float4* bp = reinterpret_cast<const float4*>(bias + r * 8);
      float4 b0 = bp[0], b1 = bp[1];
      bv[0]=b0.x; bv[1]=b0.y; bv[2]=b0.z; bv[3]=b0.w;
      bv[4]=b1.x; bv[5]=b1.y; bv[6]=b1.z; bv[7]=b1.w;
    }

    // C/D: col(fragrow)=lane&15, row=(lane>>4)*4+reg [m89]; col r of tile ot = channel r*8+ot
    #pragma unroll
    for (int j = 0; j < 4; ++j) {
      const int row = kg * 4 + j;
      u16x8 hv;
      #pragma unroll
      for (int ot = 0; ot < 8; ++ot) hv[ot] = f2bf(acc[ot][j] + bv[ot]);
      *reinterpret_cast<u16x8*>(&hb[(size_t)(n0 + row) * DIM + r * 8]) = hv;
    }
  } else {
    // ---- nhist role ----
    const int i = (bid - NHIST_B0) * 1024 + threadIdx.x;
    if (i < NNZ)
      rank_n[i] = (unsigned short)atomicAdd(&deg_n[ni[i]], 1);
  }
}

// ---------------- edge scan: per-key serial scan over chunks -> bases + totals ----------------
__global__ void escan_kernel(int* __restrict__ bh, int* __restrict__ deg_tmp) {
  int e = blockIdx.x * 256 + threadIdx.x;
  if (e >= N_EDGES) return;
  int* p = bh + (size_t)e * EH_BLOCKS;
  int base = 0;
  #pragma unroll 8
  for (int b = 0; b < EH_BLOCKS; ++b) { int t = p[b]; p[b] = base; base += t; }
  deg_tmp[e] = base;
}

// ---------------- hierarchical exclusive scan ----------------
__global__ void scan_block_kernel(const int* __restrict__ in, int* __restrict__ out,
                                  int* __restrict__ bsums, int n) {
  __shared__ int lds[512];
  const int tx = threadIdx.x;
  const int i  = blockIdx.x * blockDim.x + tx;
  int v = (i < n) ? in[i] : 0;
  int x = v;
  lds[tx] = x;
  __syncthreads();
  for (int off = 1; off < (int)blockDim.x; off <<= 1) {
    int t = (tx >= off) ? lds[tx - off] : 0;
    __syncthreads();
    x += t;
    lds[tx] = x;
    __syncthreads();
  }
  if (i < n) out[i] = x - v;                 // exclusive
  if (bsums && tx == (int)blockDim.x - 1) bsums[blockIdx.x] = x;  // total
}

__global__ void scan_add_kernel(int* __restrict__ out, const int* __restrict__ bsums, int n) {
  int i = blockIdx.x * blockDim.x + threadIdx.x;
  if (i < n) out[i] += bsums[blockIdx.x];
}

// ---------------- CSR scatter: pure stores, ranks reconstructed on the fly ----------------
__global__ void scatter_kernel(const int* __restrict__ ni, const int* __restrict__ ei,
                               const int* __restrict__ off_n, const int* __restrict__ off_e,
                               const int* __restrict__ bhE,
                               const unsigned short* __restrict__ locE,
                               const unsigned short* __restrict__ rank_n,
                               int* __restrict__ csr_e2n, int* __restrict__ csr_n2e) {
  int i = blockIdx.x * 256 + threadIdx.x;
  if (i < NNZ) {
    int n = ni[i], e = ei[i];
    int blk = i / EH_CHUNK;
    csr_e2n[off_e[e] + bhE[(size_t)e * EH_BLOCKS + blk] + (int)locE[i]] = n;
    csr_n2e[off_n[n] + (int)rank_n[i]] = e;
  }
}

// ---------------- hop 1: m01b[e,:] = bf16( sum_{n in e} h[n,:] ) ----------------
// One 16-lane group owns one edge segment serially (no LDS, no syncs).
__global__ __launch_bounds__(256) void hop1_kernel(
    const unsigned short* __restrict__ hb, const int* __restrict__ off_e,
    const int* __restrict__ csr_e2n, unsigned short* __restrict__ m01b) {
  const int e = blockIdx.x * 16 + (threadIdx.x >> 4);
  const int l = threadIdx.x & 15;
  if (e >= N_EDGES) return;
  const int s   = off_e[e];
  const int end = (e == N_EDGES - 1) ? NNZ : off_e[e + 1];

  f32x8 a0 = (f32x8){0.f,0.f,0.f,0.f,0.f,0.f,0.f,0.f};
  f32x8 a1 = a0, a2 = a0, a3 = a0;
  int j = s;
  for (; j + 3 < end; j += 4) {
    const int n0 = csr_e2n[j + 0];
    const int n1 = csr_e2n[j + 1];
    const int n2 = csr_e2n[j + 2];
    const int n3 = csr_e2n[j + 3];
    u16x8 v0 = *reinterpret_cast<const u16x8*>(&hb[(size_t)n0 * DIM + l * 8]);
    u16x8 v1 = *reinterpret_cast<const u16x8*>(&hb[(size_t)n1 * DIM + l * 8]);
    u16x8 v2 = *reinterpret_cast<const u16x8*>(&hb[(size_t)n2 * DIM + l * 8]);
    u16x8 v3 = *reinterpret_cast<const u16x8*>(&hb[(size_t)n3 * DIM + l * 8]);
    a0 += bf2f8(v0); a1 += bf2f8(v1); a2 += bf2f8(v2); a3 += bf2f8(v3);
  }
  for (; j < end; ++j) {
    const int n = csr_e2n[j];
    a0 += bf2f8(*reinterpret_cast<const u16x8*>(&hb[(size_t)n * DIM + l * 8]));
  }
  f32x8 r = (a0 + a1) + (a2 + a3);
  u16x8 o;
  #pragma unroll
  for (int i = 0; i < 8; ++i) o[i] = f2bf(r[i]);
  *reinterpret_cast<u16x8*>(&m01b[(size_t)e * DIM + l * 8]) = o;
}

// ---------------- hop 2 + finalize: out[n,:] = h[n,:] + mean_{e ni n} m01[e,:] ----------------
__global__ __launch_bounds__(256) void hop2_kernel(
    const unsigned short* __restrict__ hb, const int* __restrict__ off_n,
    const int* __restrict__ csr_n2e, const unsigned short* __restrict__ m01b,
    float* __restrict__ out) {
  const int n = blockIdx.x * 16 + (threadIdx.x >> 4);
  const int l = threadIdx.x & 15;
  if (n >= N_NODES) return;
  const int s   = off_n[n];
  const int end = (n == N_NODES - 1) ? NNZ : off_n[n + 1];
  const int cnt = end - s;

  f32x8 a0 = (f32x8){0.f,0.f,0.f,0.f,0.f,0.f,0.f,0.f};
  f32x8 a1 = a0;
  int j = s;
  for (; j + 1 < end; j += 2) {
    const int e0 = csr_n2e[j + 0];
    const int e1 = csr_n2e[j + 1];
    u16x8 v0 = *reinterpret_cast<const u16x8*>(&m01b[(size_t)e0 * DIM + l * 8]);
    u16x8 v1 = *reinterpret_cast<const u16x8*>(&m01b[(size_t)e1 * DIM + l * 8]);
    a0 += bf2f8(v0); a1 += bf2f8(v1);
  }
  if (j < end) {
    const int e = csr_n2e[j];
    a0 += bf2f8(*reinterpret_cast<const u16x8*>(&m01b[(size_t)e * DIM + l * 8]));
  }
  f32x8 r  = a0 + a1;
  f32x8 hv = bf2f8(*reinterpret_cast<const u16x8*>(&hb[(size_t)n * DIM + l * 8]));
  const float inv = 1.0f / (float)(cnt > 0 ? cnt : 1);
  f32x8 o = hv + r * inv;
  float* op = &out[(size_t)n * DIM + l * 8];
  *reinterpret_cast<f32x4*>(op)     = (f32x4){o[0], o[1], o[2], o[3]};
  *reinterpret_cast<f32x4*>(op + 4) = (f32x4){o[4], o[5], o[6], o[7]};
}

extern "C" void kernel_launch(void* const* d_in, const int* in_sizes, int n_in,
                              void* d_out, int out_size, void* d_ws, size_t ws_size,
                              hipStream_t stream) {
  const float* x    = (const float*)d_in[0];
  const float* W    = (const float*)d_in[1];
  const float* bias = (const float*)d_in[2];
  const int*   ni   = (const int*)d_in[3];
  const int*   ei   = (const int*)d_in[4];
  float* out = (float*)d_out;

  // ---- workspace carve ----
  char* ws = (char*)d_ws;
  size_t o = 0;
  auto carve = [&](size_t bytes) -> char* {
    char* p = ws + o;
    o = (o + bytes + 255) & ~(size_t)255;
    return p;
  };
  unsigned short* hb      = (unsigned short*)carve((size_t)N_NODES * DIM * 2);       // 25.6 MB
  unsigned short* m01b    = (unsigned short*)carve((size_t)N_EDGES * DIM * 2);       // 5.12 MB
  int*            csr_e2n = (int*)           carve((size_t)NNZ * 4);                 // 6.4 MB
  int*            csr_n2e = (int*)           carve((size_t)NNZ * 4);                 // 6.4 MB
  unsigned short* locE    = (unsigned short*)carve((size_t)NNZ * 2);                 // 3.2 MB
  unsigned short* rank_n  = (unsigned short*)carve((size_t)NNZ * 2);                 // 3.2 MB
  unsigned short* Wb      = (unsigned short*)carve((size_t)DIM * DIM * 2);           // 32 KB
  int*            bhE     = (int*)           carve((size_t)N_EDGES * EH_BLOCKS * 4); // 5.12 MB
  size_t zero_beg = o;
  int*            deg_n   = (int*)           carve((size_t)N_NODES * 4);             // 400 KB
  size_t zero_end = o;
  int*            deg_tmp = (int*)           carve((size_t)N_EDGES * 4);
  int*            off_n   = (int*)           carve((size_t)N_NODES * 4);
  int*            off_e   = (int*)           carve((size_t)N_EDGES * 4);
  int*            bsums   = (int*)           carve(512 * 4);
  (void)ws_size; (void)in_sizes; (void)n_in; (void)out_size;

  // ---- zero node-degree counters ----
  hipMemsetAsync(ws + zero_beg, 0, zero_end - zero_beg, stream);

  // ---- W -> bf16 ----
  convw_kernel<<<(DIM * DIM + 255) / 256, 256, 0, stream>>>(W, Wb);

  // ---- fused front end: ehist | gemm | nhist ----
  p1_kernel<<<P1_NB, 1024, 0, stream>>>(x, Wb, bias, hb, ni, ei,
                                        bhE, locE, deg_n, rank_n);

  // ---- edge per-key scan + offset scans ----
  escan_kernel<<<(N_EDGES + 255) / 256, 256, 0, stream>>>(bhE, deg_tmp);
  {
    int nbl_e = (N_EDGES + 255) / 256;   // 79
    scan_block_kernel<<<nbl_e, 256, 0, stream>>>(deg_tmp, off_e, bsums, N_EDGES);
    scan_block_kernel<<<1, 512, 0, stream>>>(bsums, bsums, nullptr, nbl_e);
    scan_add_kernel<<<nbl_e, 256, 0, stream>>>(off_e, bsums, N_EDGES);

    int nbl_n = (N_NODES + 255) / 256;   // 391
    scan_block_kernel<<<nbl_n, 256, 0, stream>>>(deg_n, off_n, bsums, N_NODES);
    scan_block_kernel<<<1, 512, 0, stream>>>(bsums, bsums, nullptr, nbl_n);
    scan_add_kernel<<<nbl_n, 256, 0, stream>>>(off_n, bsums, N_NODES);
  }

  // ---- CSR scatter (pure stores) ----
  scatter_kernel<<<NNZ / 256, 256, 0, stream>>>(ni, ei, off_n, off_e,
                                                bhE, locE, rank_n,
                                                csr_e2n, csr_n2e);

  // ---- hops ----
  hop1_kernel<<<(N_EDGES + 15) / 16, 256, 0, stream>>>(hb, off_e, csr_e2n, m01b);
  hop2_kernel<<<(N_NODES + 15) / 16, 256, 0, stream>>>(hb, off_n, csr_n2e, m01b, out);
}